// Round 6
// baseline (363.589 us; speedup 1.0000x reference)
//
#include <hip/hip_runtime.h>
#include <hip/hip_bf16.h>

#define B_  8
#define H_  512
#define L_  2048
#define D2_ 32
#define NC_ 64
#define LC_ 32    // L_/NC_
#define LCF 32    // fk kernel l-chunk

typedef __attribute__((ext_vector_type(8))) short short8;   // 8 bf16 (4 VGPRs)
typedef __attribute__((ext_vector_type(4))) float float4v;  // 4 fp32 acc

__device__ __forceinline__ float gelu_exact(float x) {
    return 0.5f * x * (1.0f + erff(x * 0.70710678118654752f));
}

__device__ __forceinline__ unsigned pack_bf16x2(float x, float y) {
    __hip_bfloat162 p = __float22bfloat162_rn(make_float2(x, y));
    return *(unsigned*)&p;
}
__device__ __forceinline__ float2 unpack_bf16x2(unsigned v) {
    __hip_bfloat162 p = *(__hip_bfloat162*)&v;
    return __bfloat1622float2(p);
}

__device__ __forceinline__ void load_lds16(const void* g, void* l) {
    __builtin_amdgcn_global_load_lds((const __attribute__((address_space(1))) unsigned int*)g,
                                     (__attribute__((address_space(3))) unsigned int*)l, 16, 0, 0);
}

// one recurrence step for all 32 states; returns qs-weighted dot
__device__ __forceinline__ float s4_step(float ul,
        const float (&wr)[D2_], const float (&wi)[D2_], const float (&qs)[D2_],
        float (&sr)[D2_], float (&si)[D2_]) {
    float d0 = 0.f, d1 = 0.f, d2 = 0.f, d3 = 0.f;
    #pragma unroll
    for (int j = 0; j < D2_; ++j) {
        float nr = fmaf(sr[j], wr[j], fmaf(-si[j], wi[j], ul));
        float ni = fmaf(sr[j], wi[j], si[j] * wr[j]);
        sr[j] = nr; si[j] = ni;
        if ((j & 3) == 0)      d0 = fmaf(qs[j], nr, d0);
        else if ((j & 3) == 1) d1 = fmaf(qs[j], nr, d1);
        else if ((j & 3) == 2) d2 = fmaf(qs[j], nr, d2);
        else                   d3 = fmaf(qs[j], nr, d3);
    }
    return (d0 + d1) + (d2 + d3);
}

__device__ __forceinline__ void s4_step_nodot(float ul,
        const float (&wr)[D2_], const float (&wi)[D2_],
        float (&sr)[D2_], float (&si)[D2_]) {
    #pragma unroll
    for (int j = 0; j < D2_; ++j) {
        float nr = fmaf(sr[j], wr[j], fmaf(-si[j], wi[j], ul));
        float ni = fmaf(sr[j], wi[j], si[j] * wr[j]);
        sr[j] = nr; si[j] = ni;
    }
}

// process 8 elements -> one uint4 of 8 packed bf16 GELU outputs
__device__ __forceinline__ uint4 s4_block8(float4 ua, float4 ub, uint4 fa, uint4 fb,
        const float (&wr)[D2_], const float (&wi)[D2_], const float (&qs)[D2_],
        float (&sr)[D2_], float (&si)[D2_], float c0, float c1, float fky_bias) {
    float us[8] = {ua.x, ua.y, ua.z, ua.w, ub.x, ub.y, ub.z, ub.w};
    unsigned fs[8] = {fa.x, fa.y, fa.z, fa.w, fb.x, fb.y, fb.z, fb.w};
    float g[8];
    #pragma unroll
    for (int e = 0; e < 8; ++e) {
        float2 fk = unpack_bf16x2(fs[e]);
        float dot = s4_step(us[e], wr, wi, qs, sr, si);
        float yv = fmaf(c0, us[e], fmaf(c1, fk.x, dot + fk.y));
        g[e] = gelu_exact(yv);
    }
    uint4 o;
    o.x = pack_bf16x2(g[0], g[1]);
    o.y = pack_bf16x2(g[2], g[3]);
    o.z = pack_bf16x2(g[4], g[5]);
    o.w = pack_bf16x2(g[6], g[7]);
    return o;
    (void)fky_bias;
}

// ---------------- cast W -> bf16, fused param prep ----------------
__global__ void cast_prep_kernel(const float* __restrict__ W, __hip_bfloat16* __restrict__ Wb,
                                 const float* __restrict__ a, const float* __restrict__ th,
                                 const float* __restrict__ bb, const float* __restrict__ cc,
                                 const float* __restrict__ x0,
                                 float* __restrict__ aT, float* __restrict__ thT,
                                 float* __restrict__ qT, float* __restrict__ gxT,
                                 float* __restrict__ WRh, float* __restrict__ WIh,
                                 float* __restrict__ QSh) {
    int tid = blockIdx.x * 256 + threadIdx.x;   // 262144
    Wb[tid] = __float2bfloat16(W[tid]);
    if (tid < H_ * D2_) {                        // tid = d*H + h (d-major)
        int h = tid & (H_ - 1);
        int d = tid >> 9;
        const float T = 1.0f / (float)(L_ - 1);
        float av = -fabsf(a[h * D2_ + d]);
        float tv = th[h * D2_ + d];
        float q  = bb[h * D2_ + d] * cc[h * D2_ + d];
        float e  = __expf(av * T);
        aT[tid]  = av;
        thT[tid] = tv;
        qT[tid]  = q;
        gxT[tid] = 2.0f * cc[h * D2_ + d] * x0[h * D2_ + d];
        WRh[h * D2_ + d] = e * __cosf(tv * T);   // h-major for scan kernels
        WIh[h * D2_ + d] = e * __sinf(tv * T);
        QSh[h * D2_ + d] = 2.0f * T * q;
    }
}

// ---------------- fk: FKf[h*L + l] = bf16x2{ f[h,l], k0[h,l] } ----------------
__global__ __launch_bounds__(256) void fk_kernel(
        const float* __restrict__ aT, const float* __restrict__ thT,
        const float* __restrict__ qT, const float* __restrict__ gxT,
        unsigned* __restrict__ FKf) {
    int t = threadIdx.x;
    int q4 = t & 3, hl = t >> 2;
    int h  = blockIdx.y * 64 + hl;
    int l0 = blockIdx.x * LCF;
    const float T = 1.0f / (float)(L_ - 1);
    float z0 = T * (float)l0;
    float pr[8], pi[8], wr[8], wi[8], qd[8], gx[8];
    #pragma unroll
    for (int j = 0; j < 8; ++j) {
        int idx = (q4 * 8 + j) * H_ + h;
        float aa = aT[idx], tv = thT[idx];
        float e0 = __expf(aa * z0);
        pr[j] = e0 * __cosf(tv * z0);
        pi[j] = e0 * __sinf(tv * z0);
        float e1 = __expf(aa * T);
        wr[j] = e1 * __cosf(tv * T);
        wi[j] = e1 * __sinf(tv * T);
        qd[j] = qT[idx];
        gx[j] = gxT[idx];
    }
    for (int i = 0; i < LCF; ++i) {
        float fa = 0.f, ka = 0.f;
        #pragma unroll
        for (int j = 0; j < 8; ++j) {
            fa = fmaf(qd[j], pr[j], fa);
            ka = fmaf(gx[j], pr[j], ka);
            float nr = fmaf(pr[j], wr[j], -(pi[j] * wi[j]));
            float ni = fmaf(pr[j], wi[j],  (pi[j] * wr[j]));
            pr[j] = nr; pi[j] = ni;
        }
        fa += __shfl_xor(fa, 1); fa += __shfl_xor(fa, 2);
        ka += __shfl_xor(ka, 1); ka += __shfl_xor(ka, 2);
        if (q4 == 0)
            FKf[(size_t)h * L_ + l0 + i] = pack_bf16x2(2.0f * T * fa, ka);
    }
}

// ---------------- Pass A: wave-per-h chunk-local scans -> E ----------------
__global__ __launch_bounds__(128) void scan_a_kernel(
        const float* __restrict__ u, const float* __restrict__ WRh,
        const float* __restrict__ WIh, unsigned* __restrict__ E) {
    int h = blockIdx.x;
    int p = blockIdx.y * 128 + threadIdx.x;   // 0..511 = (b,c)
    int b = p >> 6;
    int c = p & (NC_ - 1);
    float wr[D2_], wi[D2_];
    #pragma unroll
    for (int j = 0; j < D2_; ++j) {
        wr[j] = WRh[h * D2_ + j];   // wave-uniform -> SGPR
        wi[j] = WIh[h * D2_ + j];
    }
    float sr[D2_], si[D2_];
    #pragma unroll
    for (int j = 0; j < D2_; ++j) { sr[j] = 0.f; si[j] = 0.f; }

    const float4* up = (const float4*)(u + (size_t)(b * H_ + h) * L_ + c * LC_);
    float4 ua = up[0], ub = up[1];
    #pragma unroll
    for (int g = 0; g < 4; ++g) {
        float4 na, nb;
        if (g < 3) { na = up[2 * g + 2]; nb = up[2 * g + 3]; }
        float us[8] = {ua.x, ua.y, ua.z, ua.w, ub.x, ub.y, ub.z, ub.w};
        #pragma unroll
        for (int e = 0; e < 8; ++e)
            s4_step_nodot(us[e], wr, wi, sr, si);
        ua = na; ub = nb;
    }
    uint4* ep = (uint4*)(E + ((size_t)(b * H_ + h) * NC_ + c) * D2_);
    #pragma unroll
    for (int k = 0; k < 8; ++k) {
        uint4 ev;
        ev.x = pack_bf16x2(sr[4 * k + 0], si[4 * k + 0]);
        ev.y = pack_bf16x2(sr[4 * k + 1], si[4 * k + 1]);
        ev.z = pack_bf16x2(sr[4 * k + 2], si[4 * k + 2]);
        ev.w = pack_bf16x2(sr[4 * k + 3], si[4 * k + 3]);
        ep[k] = ev;
    }
}

// ---------------- combine: in-place E[c] -> carry ENTERING chunk c ----------------
__global__ __launch_bounds__(256) void combine_kernel(
        const float* __restrict__ a, const float* __restrict__ th,
        unsigned* __restrict__ E) {
    int tid = blockIdx.x * 256 + threadIdx.x;   // B_*H_*D2_ = 131072
    int d  = tid & (D2_ - 1);
    int bh = tid >> 5;
    int h  = bh & (H_ - 1);
    const float T = 1.0f / (float)(L_ - 1);
    float aa  = -fabsf(a[h * D2_ + d]);
    float eC  = __expf(aa * T * (float)LC_);
    float tC  = th[h * D2_ + d] * T * (float)LC_;
    float Wr  = eC * __cosf(tC);
    float Wi  = eC * __sinf(tC);
    float sr = 0.f, si = 0.f;
    for (int c0 = 0; c0 < NC_; c0 += 8) {
        float2 e[8];
        #pragma unroll
        for (int k = 0; k < 8; ++k)
            e[k] = unpack_bf16x2(E[((size_t)bh * NC_ + c0 + k) * D2_ + d]);
        #pragma unroll
        for (int k = 0; k < 8; ++k) {
            E[((size_t)bh * NC_ + c0 + k) * D2_ + d] = pack_bf16x2(sr, si);
            float nr = fmaf(sr, Wr, fmaf(-si, Wi, e[k].x));
            float ni = fmaf(sr, Wi, fmaf(si, Wr, e[k].y));
            sr = nr; si = ni;
        }
    }
}

// ---------------- Pass B: wave-per-h full scan, fused epilogue, y[b][h][l] ----------------
__global__ __launch_bounds__(128) void scan_b_kernel(
        const float* __restrict__ u, const float* __restrict__ WRh,
        const float* __restrict__ WIh, const float* __restrict__ QSh,
        const float* __restrict__ Dp, const unsigned* __restrict__ E,
        const unsigned* __restrict__ FKf, __hip_bfloat16* __restrict__ y) {
    int h = blockIdx.x;
    int p = blockIdx.y * 128 + threadIdx.x;   // (b,c)
    int b = p >> 6;
    int c = p & (NC_ - 1);

    float wr[D2_], wi[D2_], qs[D2_];
    float f0 = 0.f;
    #pragma unroll
    for (int j = 0; j < D2_; ++j) {
        wr[j] = WRh[h * D2_ + j];   // wave-uniform -> SGPR
        wi[j] = WIh[h * D2_ + j];
        qs[j] = QSh[h * D2_ + j];
        f0 += qs[j];
    }
    float Dh = Dp[h];
    float u0 = u[(size_t)(b * H_ + h) * L_];
    float c0 = Dh - 0.5f * f0;      // coeff of u[l]
    float c1 = -0.5f * u0;          // coeff of f[l]

    float sr[D2_], si[D2_];
    const uint4* ep = (const uint4*)(E + ((size_t)(b * H_ + h) * NC_ + c) * D2_);
    #pragma unroll
    for (int k = 0; k < 8; ++k) {
        uint4 ev = ep[k];
        float2 s0 = unpack_bf16x2(ev.x), s1 = unpack_bf16x2(ev.y);
        float2 s2 = unpack_bf16x2(ev.z), s3 = unpack_bf16x2(ev.w);
        sr[4*k+0] = s0.x; si[4*k+0] = s0.y;
        sr[4*k+1] = s1.x; si[4*k+1] = s1.y;
        sr[4*k+2] = s2.x; si[4*k+2] = s2.y;
        sr[4*k+3] = s3.x; si[4*k+3] = s3.y;
    }

    const float4* up = (const float4*)(u + (size_t)(b * H_ + h) * L_ + c * LC_);
    const uint4*  fp = (const uint4*)(FKf + (size_t)h * L_ + c * LC_);
    uint4* yp = (uint4*)(y + (size_t)(b * H_ + h) * L_ + c * LC_);

    float4 ua0 = up[0], ua1 = up[1];
    uint4  fa0 = fp[0], fa1 = fp[1];
    float4 ub0 = up[2], ub1 = up[3];
    uint4  fb0 = fp[2], fb1 = fp[3];
    uint4 o0 = s4_block8(ua0, ua1, fa0, fa1, wr, wi, qs, sr, si, c0, c1, 0.f);
    float4 uc0 = up[4], uc1 = up[5];
    uint4  fc0 = fp[4], fc1 = fp[5];
    uint4 o1 = s4_block8(ub0, ub1, fb0, fb1, wr, wi, qs, sr, si, c0, c1, 0.f);
    float4 ud0 = up[6], ud1 = up[7];
    uint4  fd0 = fp[6], fd1 = fp[7];
    uint4 o2 = s4_block8(uc0, uc1, fc0, fc1, wr, wi, qs, sr, si, c0, c1, 0.f);
    uint4 o3 = s4_block8(ud0, ud1, fd0, fd1, wr, wi, qs, sr, si, c0, c1, 0.f);
    // lane's chunk = exactly one 64B line, written back-to-back
    yp[0] = o0; yp[1] = o1; yp[2] = o2; yp[3] = o3;
}

// ---------------- transpose y[b][f][l] -> yT[b][l][f] (bf16) ----------------
__global__ __launch_bounds__(256) void transpose_y_kernel(
        const __hip_bfloat16* __restrict__ y, __hip_bfloat16* __restrict__ yT) {
    __shared__ short tile[64][72];
    int l0 = blockIdx.x * 64, f0 = blockIdx.y * 64, b = blockIdx.z;
    int t = threadIdx.x;
    int row = t >> 3, col8 = (t & 7) * 8;
    const short* yg = (const short*)y + (size_t)b * H_ * L_;
    #pragma unroll
    for (int r2 = 0; r2 < 64; r2 += 32)
        *(uint4*)&tile[row + r2][col8] =
            *(const uint4*)&yg[(size_t)(f0 + row + r2) * L_ + l0 + col8];
    __syncthreads();
    short* og = (short*)yT + (size_t)b * L_ * H_;
    #pragma unroll
    for (int r2 = 0; r2 < 64; r2 += 32) {
        int lrow = row + r2;
        short v[8];
        #pragma unroll
        for (int j = 0; j < 8; ++j) v[j] = tile[col8 + j][lrow];
        *(uint4*)&og[(size_t)(l0 + lrow) * H_ + f0 + col8] = *(uint4*)v;
    }
}

// ---------------- gemm: out[b,h,l] = sum_f W[h,f] * yT[b,l,f] + bias[h] ----------------
__global__ __launch_bounds__(256) void gemm_kernel(
        const __hip_bfloat16* __restrict__ Wb, const __hip_bfloat16* __restrict__ yT,
        const float* __restrict__ bias, float* __restrict__ out) {
    __shared__ __align__(16) short As[128 * 32];
    __shared__ __align__(16) short Bs[128 * 32];
    int l0 = blockIdx.x * 128;
    int h0 = blockIdx.y * 128;
    int b  = blockIdx.z;
    int t    = threadIdx.x;
    int lane = t & 63, wave = t >> 6;
    int m_off = (wave >> 1) * 64, n_off = (wave & 1) * 64;
    int quad = lane >> 4, ln = lane & 15;

    float4v acc[4][4];
    #pragma unroll
    for (int mt = 0; mt < 4; ++mt)
        #pragma unroll
        for (int nt = 0; nt < 4; ++nt)
            acc[mt][nt] = (float4v){0.f, 0.f, 0.f, 0.f};

    const short* Wg = (const short*)Wb;
    const short* Yg = (const short*)(yT + (size_t)b * L_ * H_);

    int r  = t >> 2;
    int qd = t & 3;

    for (int kt = 0; kt < 16; ++kt) {
        int k0 = kt * 32;
        load_lds16(Wg + (h0 + r)      * 512 + k0 + qd * 8, &As[t * 8]);
        load_lds16(Wg + (h0 + r + 64) * 512 + k0 + qd * 8, &As[(t + 256) * 8]);
        load_lds16(Yg + (size_t)(l0 + r)      * 512 + k0 + qd * 8, &Bs[t * 8]);
        load_lds16(Yg + (size_t)(l0 + r + 64) * 512 + k0 + qd * 8, &Bs[(t + 256) * 8]);
        __syncthreads();

        short8 af[4], bf[4];
        #pragma unroll
        for (int mt = 0; mt < 4; ++mt)
            af[mt] = *(const short8*)&As[(m_off + mt * 16 + ln) * 32 + quad * 8];
        #pragma unroll
        for (int nt = 0; nt < 4; ++nt)
            bf[nt] = *(const short8*)&Bs[(n_off + nt * 16 + ln) * 32 + quad * 8];
        #pragma unroll
        for (int mt = 0; mt < 4; ++mt)
            #pragma unroll
            for (int nt = 0; nt < 4; ++nt)
                acc[mt][nt] = __builtin_amdgcn_mfma_f32_16x16x32_bf16(
                    af[mt], bf[nt], acc[mt][nt], 0, 0, 0);
        __syncthreads();
    }

    #pragma unroll
    for (int mt = 0; mt < 4; ++mt) {
        #pragma unroll
        for (int nt = 0; nt < 4; ++nt) {
            int hh = h0 + m_off + mt * 16 + quad * 4;
            int ll = l0 + n_off + nt * 16 + ln;
            #pragma unroll
            for (int r2 = 0; r2 < 4; ++r2)
                out[((size_t)(b * H_ + hh + r2)) * L_ + ll] = acc[mt][nt][r2] + bias[hh + r2];
        }
    }
}

extern "C" void kernel_launch(void* const* d_in, const int* in_sizes, int n_in,
                              void* d_out, int out_size, void* d_ws, size_t ws_size,
                              hipStream_t stream) {
    const float* u    = (const float*)d_in[0];
    const float* a    = (const float*)d_in[1];
    const float* th   = (const float*)d_in[2];
    const float* bb   = (const float*)d_in[3];
    const float* cc   = (const float*)d_in[4];
    const float* x0   = (const float*)d_in[5];
    const float* Dp   = (const float*)d_in[6];
    const float* W    = (const float*)d_in[7];
    const float* bias = (const float*)d_in[8];
    float* out = (float*)d_out;
    char* ws = (char*)d_ws;

    // layout (53 MiB): FKf 4M @0 | E 32M @4M | y 16M @36M | Wb 0.5M @52M | params @52.5M
    // yT 16M @4M — ALIASES E: E is last read by scan_b, which completes before
    // transpose_y writes yT (sequential stream). ws_size >= 57 MiB proven in R3.
    unsigned*       FKf = (unsigned*)ws;
    unsigned*       E   = (unsigned*)(ws + (4ull  << 20));
    __hip_bfloat16* yT  = (__hip_bfloat16*)(ws + (4ull  << 20));
    __hip_bfloat16* y   = (__hip_bfloat16*)(ws + (36ull << 20));
    __hip_bfloat16* Wb  = (__hip_bfloat16*)(ws + (52ull << 20));
    float* pbase = (float*)(ws + (52ull << 20) + (512ull << 10));
    float *aT  = pbase,            *thT = pbase + 16384,   *qT  = pbase + 2*16384,
          *gxT = pbase + 3*16384,  *WRh = pbase + 4*16384, *WIh = pbase + 5*16384,
          *QSh = pbase + 6*16384;

    hipLaunchKernelGGL(cast_prep_kernel,  dim3(1024),      dim3(256), 0, stream,
                       W, Wb, a, th, bb, cc, x0, aT, thT, qT, gxT, WRh, WIh, QSh);
    hipLaunchKernelGGL(fk_kernel,         dim3(L_/LCF, 8), dim3(256), 0, stream,
                       aT, thT, qT, gxT, FKf);
    hipLaunchKernelGGL(scan_a_kernel,     dim3(H_, 4),     dim3(128), 0, stream,
                       u, WRh, WIh, E);
    hipLaunchKernelGGL(combine_kernel,    dim3(512),       dim3(256), 0, stream, a, th, E);
    hipLaunchKernelGGL(scan_b_kernel,     dim3(H_, 4),     dim3(128), 0, stream,
                       u, WRh, WIh, QSh, Dp, E, FKf, y);
    hipLaunchKernelGGL(transpose_y_kernel,dim3(32, 8, 8),  dim3(256), 0, stream, y, yT);
    hipLaunchKernelGGL(gemm_kernel,       dim3(16, 4, 8),  dim3(256), 0, stream,
                       Wb, yT, bias, out);
}

// Round 7
// 222.459 us; speedup vs baseline: 1.6344x; 1.6344x over previous
//
#include <hip/hip_runtime.h>
#include <hip/hip_bf16.h>

#define B_  8
#define H_  512
#define L_  2048
#define D2_ 32
#define NC_ 32
#define LC_ 64    // L_/NC_
#define LCF 32    // fk kernel l-chunk

typedef __attribute__((ext_vector_type(8))) short short8;   // 8 bf16 (4 VGPRs)
typedef __attribute__((ext_vector_type(4))) float float4v;  // 4 fp32 acc

__device__ __forceinline__ float gelu_exact(float x) {
    return 0.5f * x * (1.0f + erff(x * 0.70710678118654752f));
}

__device__ __forceinline__ unsigned pack_bf16x2(float x, float y) {
    __hip_bfloat162 p = __float22bfloat162_rn(make_float2(x, y));
    return *(unsigned*)&p;
}
__device__ __forceinline__ float2 unpack_bf16x2(unsigned v) {
    __hip_bfloat162 p = *(__hip_bfloat162*)&v;
    return __bfloat1622float2(p);
}

__device__ __forceinline__ void load_lds16(const void* g, void* l) {
    __builtin_amdgcn_global_load_lds((const __attribute__((address_space(1))) unsigned int*)g,
                                     (__attribute__((address_space(3))) unsigned int*)l, 16, 0, 0);
}

// unpack uint4 of 8 bf16 -> 8 floats
__device__ __forceinline__ void unpack_u8(uint4 v, float (&us)[8]) {
    float2 a0 = unpack_bf16x2(v.x), a1 = unpack_bf16x2(v.y);
    float2 a2 = unpack_bf16x2(v.z), a3 = unpack_bf16x2(v.w);
    us[0] = a0.x; us[1] = a0.y; us[2] = a1.x; us[3] = a1.y;
    us[4] = a2.x; us[5] = a2.y; us[6] = a3.x; us[7] = a3.y;
}

// one recurrence step for all 32 states; returns qs-weighted dot
__device__ __forceinline__ float s4_step(float ul,
        const float (&wr)[D2_], const float (&wi)[D2_], const float (&qs)[D2_],
        float (&sr)[D2_], float (&si)[D2_]) {
    float d0 = 0.f, d1 = 0.f, d2 = 0.f, d3 = 0.f;
    #pragma unroll
    for (int j = 0; j < D2_; ++j) {
        float nr = fmaf(sr[j], wr[j], fmaf(-si[j], wi[j], ul));
        float ni = fmaf(sr[j], wi[j], si[j] * wr[j]);
        sr[j] = nr; si[j] = ni;
        if ((j & 3) == 0)      d0 = fmaf(qs[j], nr, d0);
        else if ((j & 3) == 1) d1 = fmaf(qs[j], nr, d1);
        else if ((j & 3) == 2) d2 = fmaf(qs[j], nr, d2);
        else                   d3 = fmaf(qs[j], nr, d3);
    }
    return (d0 + d1) + (d2 + d3);
}

__device__ __forceinline__ void s4_step_nodot(float ul,
        const float (&wr)[D2_], const float (&wi)[D2_],
        float (&sr)[D2_], float (&si)[D2_]) {
    #pragma unroll
    for (int j = 0; j < D2_; ++j) {
        float nr = fmaf(sr[j], wr[j], fmaf(-si[j], wi[j], ul));
        float ni = fmaf(sr[j], wi[j], si[j] * wr[j]);
        sr[j] = nr; si[j] = ni;
    }
}

// 8 elements (one coalesced uint4 of u, two uint4 of fk) -> uint4 of 8 bf16 GELU outs
__device__ __forceinline__ uint4 s4_block8(uint4 uv, uint4 fa, uint4 fb,
        const float (&wr)[D2_], const float (&wi)[D2_], const float (&qs)[D2_],
        float (&sr)[D2_], float (&si)[D2_], float c0, float c1) {
    float us[8];
    unpack_u8(uv, us);
    unsigned fs[8] = {fa.x, fa.y, fa.z, fa.w, fb.x, fb.y, fb.z, fb.w};
    float g[8];
    #pragma unroll
    for (int e = 0; e < 8; ++e) {
        float2 fk = unpack_bf16x2(fs[e]);
        float dot = s4_step(us[e], wr, wi, qs, sr, si);
        float yv = fmaf(c0, us[e], fmaf(c1, fk.x, dot + fk.y));
        g[e] = gelu_exact(yv);
    }
    uint4 o;
    o.x = pack_bf16x2(g[0], g[1]);
    o.y = pack_bf16x2(g[2], g[3]);
    o.z = pack_bf16x2(g[4], g[5]);
    o.w = pack_bf16x2(g[6], g[7]);
    return o;
}

// ---------------- cast W -> bf16, fused param prep ----------------
__global__ void cast_prep_kernel(const float* __restrict__ W, __hip_bfloat16* __restrict__ Wb,
                                 const float* __restrict__ a, const float* __restrict__ th,
                                 const float* __restrict__ bb, const float* __restrict__ cc,
                                 const float* __restrict__ x0,
                                 float* __restrict__ aT, float* __restrict__ thT,
                                 float* __restrict__ qT, float* __restrict__ gxT,
                                 float* __restrict__ WRh, float* __restrict__ WIh,
                                 float* __restrict__ QSh) {
    int tid = blockIdx.x * 256 + threadIdx.x;   // 262144
    Wb[tid] = __float2bfloat16(W[tid]);
    if (tid < H_ * D2_) {                        // tid = d*H + h (d-major)
        int h = tid & (H_ - 1);
        int d = tid >> 9;
        const float T = 1.0f / (float)(L_ - 1);
        float av = -fabsf(a[h * D2_ + d]);
        float tv = th[h * D2_ + d];
        float q  = bb[h * D2_ + d] * cc[h * D2_ + d];
        float e  = __expf(av * T);
        aT[tid]  = av;
        thT[tid] = tv;
        qT[tid]  = q;
        gxT[tid] = 2.0f * cc[h * D2_ + d] * x0[h * D2_ + d];
        WRh[h * D2_ + d] = e * __cosf(tv * T);   // h-major for scan kernels
        WIh[h * D2_ + d] = e * __sinf(tv * T);
        QSh[h * D2_ + d] = 2.0f * T * q;
    }
}

// ---------------- permute u[b][h][l] -> uP bf16, 8-pack chunk-interleaved ----------------
// flat8(l) = (i>>3)*256 + c*8 + (i&7)  with c = l>>6 (chunk), i = l&63
__global__ __launch_bounds__(256) void permute_u_kernel(
        const float* __restrict__ u, __hip_bfloat16* __restrict__ uP) {
    __shared__ float tile[32][65];
    int bh = blockIdx.x;
    int t = threadIdx.x;
    const float* ur = u + (size_t)bh * L_;
    #pragma unroll
    for (int k = 0; k < 8; ++k) {
        int l = t + k * 256;
        tile[l >> 6][l & 63] = ur[l];
    }
    __syncthreads();
    unsigned* op = (unsigned*)(uP + (size_t)bh * L_);
    #pragma unroll
    for (int k = 0; k < 4; ++k) {
        int jj = t + k * 256;        // packed-pair index
        int j = jj * 2;              // bf16 flat index (even)
        int g = j >> 8, c = (j >> 3) & 31, r = j & 7;
        int i = g * 8 + r;
        op[jj] = pack_bf16x2(tile[c][i], tile[c][i + 1]);
    }
}

// ---------------- fk: FKp 4-pack chunk-interleaved bf16x2{ f, k0 } ----------------
// flat4(l) = (i>>2)*128 + c*4 + (i&3)
__global__ __launch_bounds__(256) void fk_kernel(
        const float* __restrict__ aT, const float* __restrict__ thT,
        const float* __restrict__ qT, const float* __restrict__ gxT,
        unsigned* __restrict__ FKp) {
    int t = threadIdx.x;
    int q4 = t & 3, hl = t >> 2;
    int h  = blockIdx.y * 64 + hl;
    int l0 = blockIdx.x * LCF;
    const float T = 1.0f / (float)(L_ - 1);
    float z0 = T * (float)l0;
    float pr[8], pi[8], wr[8], wi[8], qd[8], gx[8];
    #pragma unroll
    for (int j = 0; j < 8; ++j) {
        int idx = (q4 * 8 + j) * H_ + h;
        float aa = aT[idx], tv = thT[idx];
        float e0 = __expf(aa * z0);
        pr[j] = e0 * __cosf(tv * z0);
        pi[j] = e0 * __sinf(tv * z0);
        float e1 = __expf(aa * T);
        wr[j] = e1 * __cosf(tv * T);
        wi[j] = e1 * __sinf(tv * T);
        qd[j] = qT[idx];
        gx[j] = gxT[idx];
    }
    for (int il = 0; il < LCF; ++il) {
        float fa = 0.f, ka = 0.f;
        #pragma unroll
        for (int j = 0; j < 8; ++j) {
            fa = fmaf(qd[j], pr[j], fa);
            ka = fmaf(gx[j], pr[j], ka);
            float nr = fmaf(pr[j], wr[j], -(pi[j] * wi[j]));
            float ni = fmaf(pr[j], wi[j],  (pi[j] * wr[j]));
            pr[j] = nr; pi[j] = ni;
        }
        fa += __shfl_xor(fa, 1); fa += __shfl_xor(fa, 2);
        ka += __shfl_xor(ka, 1); ka += __shfl_xor(ka, 2);
        if (q4 == 0) {
            int l = l0 + il;
            int c = l >> 6, ii = l & 63;
            int flat = (ii >> 2) * 128 + c * 4 + (ii & 3);
            FKp[(size_t)h * L_ + flat] = pack_bf16x2(2.0f * T * fa, ka);
        }
    }
}

// ---------------- Pass A: wave-per-h chunk-local scans, coalesced uP ----------------
__global__ __launch_bounds__(128) void scan_a_kernel(
        const __hip_bfloat16* __restrict__ uP, const float* __restrict__ WRh,
        const float* __restrict__ WIh, unsigned* __restrict__ E) {
    int h = blockIdx.x;
    int p = blockIdx.y * 128 + threadIdx.x;   // 0..255 = (b,c)
    int b = p >> 5;
    int c = p & (NC_ - 1);
    float wr[D2_], wi[D2_];
    #pragma unroll
    for (int j = 0; j < D2_; ++j) {
        wr[j] = WRh[h * D2_ + j];   // wave-uniform -> SGPR
        wi[j] = WIh[h * D2_ + j];
    }
    float sr[D2_], si[D2_];
    #pragma unroll
    for (int j = 0; j < D2_; ++j) { sr[j] = 0.f; si[j] = 0.f; }

    const uint4* up = (const uint4*)(uP + (size_t)(b * H_ + h) * L_);
    #pragma unroll
    for (int g = 0; g < 8; ++g) {
        uint4 uv = up[g * 32 + c];          // coalesced per wave
        float us[8];
        unpack_u8(uv, us);
        #pragma unroll
        for (int e = 0; e < 8; ++e)
            s4_step_nodot(us[e], wr, wi, sr, si);
    }
    uint4* ep = (uint4*)(E + ((size_t)(b * H_ + h) * NC_ + c) * D2_);
    #pragma unroll
    for (int k = 0; k < 8; ++k) {
        uint4 ev;
        ev.x = pack_bf16x2(sr[4 * k + 0], si[4 * k + 0]);
        ev.y = pack_bf16x2(sr[4 * k + 1], si[4 * k + 1]);
        ev.z = pack_bf16x2(sr[4 * k + 2], si[4 * k + 2]);
        ev.w = pack_bf16x2(sr[4 * k + 3], si[4 * k + 3]);
        ep[k] = ev;
    }
}

// ---------------- combine: in-place E[c] -> carry ENTERING chunk c ----------------
__global__ __launch_bounds__(256) void combine_kernel(
        const float* __restrict__ a, const float* __restrict__ th,
        unsigned* __restrict__ E) {
    int tid = blockIdx.x * 256 + threadIdx.x;   // B_*H_*D2_ = 131072
    int d  = tid & (D2_ - 1);
    int bh = tid >> 5;
    int h  = bh & (H_ - 1);
    const float T = 1.0f / (float)(L_ - 1);
    float aa  = -fabsf(a[h * D2_ + d]);
    float eC  = __expf(aa * T * (float)LC_);
    float tC  = th[h * D2_ + d] * T * (float)LC_;
    float Wr  = eC * __cosf(tC);
    float Wi  = eC * __sinf(tC);
    float sr = 0.f, si = 0.f;
    for (int c0 = 0; c0 < NC_; c0 += 8) {
        float2 e[8];
        #pragma unroll
        for (int k = 0; k < 8; ++k)
            e[k] = unpack_bf16x2(E[((size_t)bh * NC_ + c0 + k) * D2_ + d]);
        #pragma unroll
        for (int k = 0; k < 8; ++k) {
            E[((size_t)bh * NC_ + c0 + k) * D2_ + d] = pack_bf16x2(sr, si);
            float nr = fmaf(sr, Wr, fmaf(-si, Wi, e[k].x));
            float ni = fmaf(sr, Wi, fmaf(si, Wr, e[k].y));
            sr = nr; si = ni;
        }
    }
}

// ---------------- Pass B: wave-per-h full scan, coalesced loads, y[b][h][l] ----------------
__global__ __launch_bounds__(128) void scan_b_kernel(
        const float* __restrict__ u, const __hip_bfloat16* __restrict__ uP,
        const float* __restrict__ WRh, const float* __restrict__ WIh,
        const float* __restrict__ QSh, const float* __restrict__ Dp,
        const unsigned* __restrict__ E, const unsigned* __restrict__ FKp,
        __hip_bfloat16* __restrict__ y) {
    int h = blockIdx.x;
    int p = blockIdx.y * 128 + threadIdx.x;   // (b,c)
    int b = p >> 5;
    int c = p & (NC_ - 1);

    float wr[D2_], wi[D2_], qs[D2_];
    float f0 = 0.f;
    #pragma unroll
    for (int j = 0; j < D2_; ++j) {
        wr[j] = WRh[h * D2_ + j];   // wave-uniform -> SGPR
        wi[j] = WIh[h * D2_ + j];
        qs[j] = QSh[h * D2_ + j];
        f0 += qs[j];
    }
    float Dh = Dp[h];
    float u0 = u[(size_t)(b * H_ + h) * L_];
    float c0 = Dh - 0.5f * f0;      // coeff of u[l]
    float c1 = -0.5f * u0;          // coeff of f[l]

    float sr[D2_], si[D2_];
    const uint4* ep = (const uint4*)(E + ((size_t)(b * H_ + h) * NC_ + c) * D2_);
    #pragma unroll
    for (int k = 0; k < 8; ++k) {
        uint4 ev = ep[k];
        float2 s0 = unpack_bf16x2(ev.x), s1 = unpack_bf16x2(ev.y);
        float2 s2 = unpack_bf16x2(ev.z), s3 = unpack_bf16x2(ev.w);
        sr[4*k+0] = s0.x; si[4*k+0] = s0.y;
        sr[4*k+1] = s1.x; si[4*k+1] = s1.y;
        sr[4*k+2] = s2.x; si[4*k+2] = s2.y;
        sr[4*k+3] = s3.x; si[4*k+3] = s3.y;
    }

    const uint4* upv = (const uint4*)(uP + (size_t)(b * H_ + h) * L_);
    const uint4* fqv = (const uint4*)(FKp + (size_t)h * L_);
    uint4* yp = (uint4*)(y + (size_t)(b * H_ + h) * L_) + c * 8;

    uint4 o0 = s4_block8(upv[0*32+c], fqv[0*64+c], fqv[0*64+32+c], wr, wi, qs, sr, si, c0, c1);
    uint4 o1 = s4_block8(upv[1*32+c], fqv[1*64+c], fqv[1*64+32+c], wr, wi, qs, sr, si, c0, c1);
    uint4 o2 = s4_block8(upv[2*32+c], fqv[2*64+c], fqv[2*64+32+c], wr, wi, qs, sr, si, c0, c1);
    uint4 o3 = s4_block8(upv[3*32+c], fqv[3*64+c], fqv[3*64+32+c], wr, wi, qs, sr, si, c0, c1);
    yp[0] = o0; yp[1] = o1; yp[2] = o2; yp[3] = o3;     // 64B back-to-back
    uint4 o4 = s4_block8(upv[4*32+c], fqv[4*64+c], fqv[4*64+32+c], wr, wi, qs, sr, si, c0, c1);
    uint4 o5 = s4_block8(upv[5*32+c], fqv[5*64+c], fqv[5*64+32+c], wr, wi, qs, sr, si, c0, c1);
    uint4 o6 = s4_block8(upv[6*32+c], fqv[6*64+c], fqv[6*64+32+c], wr, wi, qs, sr, si, c0, c1);
    uint4 o7 = s4_block8(upv[7*32+c], fqv[7*64+c], fqv[7*64+32+c], wr, wi, qs, sr, si, c0, c1);
    yp[4] = o4; yp[5] = o5; yp[6] = o6; yp[7] = o7;
}

// ---------------- transpose y[b][f][l] -> yT[b][l][f] (bf16) ----------------
__global__ __launch_bounds__(256) void transpose_y_kernel(
        const __hip_bfloat16* __restrict__ y, __hip_bfloat16* __restrict__ yT) {
    __shared__ short tile[64][72];
    int l0 = blockIdx.x * 64, f0 = blockIdx.y * 64, b = blockIdx.z;
    int t = threadIdx.x;
    int row = t >> 3, col8 = (t & 7) * 8;
    const short* yg = (const short*)y + (size_t)b * H_ * L_;
    #pragma unroll
    for (int r2 = 0; r2 < 64; r2 += 32)
        *(uint4*)&tile[row + r2][col8] =
            *(const uint4*)&yg[(size_t)(f0 + row + r2) * L_ + l0 + col8];
    __syncthreads();
    short* og = (short*)yT + (size_t)b * L_ * H_;
    #pragma unroll
    for (int r2 = 0; r2 < 64; r2 += 32) {
        int lrow = row + r2;
        short v[8];
        #pragma unroll
        for (int j = 0; j < 8; ++j) v[j] = tile[col8 + j][lrow];
        *(uint4*)&og[(size_t)(l0 + lrow) * H_ + f0 + col8] = *(uint4*)v;
    }
}

// ---------------- gemm: out[b,h,l] = sum_f W[h,f] * yT[b,l,f] + bias[h] ----------------
__global__ __launch_bounds__(256) void gemm_kernel(
        const __hip_bfloat16* __restrict__ Wb, const __hip_bfloat16* __restrict__ yT,
        const float* __restrict__ bias, float* __restrict__ out) {
    __shared__ __align__(16) short As[128 * 32];
    __shared__ __align__(16) short Bs[128 * 32];
    int l0 = blockIdx.x * 128;
    int h0 = blockIdx.y * 128;
    int b  = blockIdx.z;
    int t    = threadIdx.x;
    int lane = t & 63, wave = t >> 6;
    int m_off = (wave >> 1) * 64, n_off = (wave & 1) * 64;
    int quad = lane >> 4, ln = lane & 15;

    float4v acc[4][4];
    #pragma unroll
    for (int mt = 0; mt < 4; ++mt)
        #pragma unroll
        for (int nt = 0; nt < 4; ++nt)
            acc[mt][nt] = (float4v){0.f, 0.f, 0.f, 0.f};

    const short* Wg = (const short*)Wb;
    const short* Yg = (const short*)(yT + (size_t)b * L_ * H_);

    int r  = t >> 2;
    int qd = t & 3;

    for (int kt = 0; kt < 16; ++kt) {
        int k0 = kt * 32;
        load_lds16(Wg + (h0 + r)      * 512 + k0 + qd * 8, &As[t * 8]);
        load_lds16(Wg + (h0 + r + 64) * 512 + k0 + qd * 8, &As[(t + 256) * 8]);
        load_lds16(Yg + (size_t)(l0 + r)      * 512 + k0 + qd * 8, &Bs[t * 8]);
        load_lds16(Yg + (size_t)(l0 + r + 64) * 512 + k0 + qd * 8, &Bs[(t + 256) * 8]);
        __syncthreads();

        short8 af[4], bf[4];
        #pragma unroll
        for (int mt = 0; mt < 4; ++mt)
            af[mt] = *(const short8*)&As[(m_off + mt * 16 + ln) * 32 + quad * 8];
        #pragma unroll
        for (int nt = 0; nt < 4; ++nt)
            bf[nt] = *(const short8*)&Bs[(n_off + nt * 16 + ln) * 32 + quad * 8];
        #pragma unroll
        for (int mt = 0; mt < 4; ++mt)
            #pragma unroll
            for (int nt = 0; nt < 4; ++nt)
                acc[mt][nt] = __builtin_amdgcn_mfma_f32_16x16x32_bf16(
                    af[mt], bf[nt], acc[mt][nt], 0, 0, 0);
        __syncthreads();
    }

    #pragma unroll
    for (int mt = 0; mt < 4; ++mt) {
        #pragma unroll
        for (int nt = 0; nt < 4; ++nt) {
            int hh = h0 + m_off + mt * 16 + quad * 4;
            int ll = l0 + n_off + nt * 16 + ln;
            #pragma unroll
            for (int r2 = 0; r2 < 4; ++r2)
                out[((size_t)(b * H_ + hh + r2)) * L_ + ll] = acc[mt][nt][r2] + bias[hh + r2];
        }
    }
}

extern "C" void kernel_launch(void* const* d_in, const int* in_sizes, int n_in,
                              void* d_out, int out_size, void* d_ws, size_t ws_size,
                              hipStream_t stream) {
    const float* u    = (const float*)d_in[0];
    const float* a    = (const float*)d_in[1];
    const float* th   = (const float*)d_in[2];
    const float* bb   = (const float*)d_in[3];
    const float* cc   = (const float*)d_in[4];
    const float* x0   = (const float*)d_in[5];
    const float* Dp   = (const float*)d_in[6];
    const float* W    = (const float*)d_in[7];
    const float* bias = (const float*)d_in[8];
    float* out = (float*)d_out;
    char* ws = (char*)d_ws;

    // layout (~53 MB): uP 16M @0 | FKp 4M @16M | E 16M @20M | y 16M @36M | Wb 0.5M @52M
    // | params @52.5M.  yT 16M @20M ALIASES E (E last read by scan_b; transpose_y
    // writes yT afterwards — sequential stream). ws_size >= 57 MiB proven in R3.
    __hip_bfloat16* uP  = (__hip_bfloat16*)ws;
    unsigned*       FKp = (unsigned*)(ws + (16ull << 20));
    unsigned*       E   = (unsigned*)(ws + (20ull << 20));
    __hip_bfloat16* yT  = (__hip_bfloat16*)(ws + (20ull << 20));
    __hip_bfloat16* y   = (__hip_bfloat16*)(ws + (36ull << 20));
    __hip_bfloat16* Wb  = (__hip_bfloat16*)(ws + (52ull << 20));
    float* pbase = (float*)(ws + (52ull << 20) + (512ull << 10));
    float *aT  = pbase,            *thT = pbase + 16384,   *qT  = pbase + 2*16384,
          *gxT = pbase + 3*16384,  *WRh = pbase + 4*16384, *WIh = pbase + 5*16384,
          *QSh = pbase + 6*16384;

    hipLaunchKernelGGL(cast_prep_kernel,  dim3(1024),      dim3(256), 0, stream,
                       W, Wb, a, th, bb, cc, x0, aT, thT, qT, gxT, WRh, WIh, QSh);
    hipLaunchKernelGGL(permute_u_kernel,  dim3(B_ * H_),   dim3(256), 0, stream, u, uP);
    hipLaunchKernelGGL(fk_kernel,         dim3(L_/LCF, 8), dim3(256), 0, stream,
                       aT, thT, qT, gxT, FKp);
    hipLaunchKernelGGL(scan_a_kernel,     dim3(H_, 2),     dim3(128), 0, stream,
                       uP, WRh, WIh, E);
    hipLaunchKernelGGL(combine_kernel,    dim3(512),       dim3(256), 0, stream, a, th, E);
    hipLaunchKernelGGL(scan_b_kernel,     dim3(H_, 2),     dim3(128), 0, stream,
                       u, uP, WRh, WIh, QSh, Dp, E, FKp, y);
    hipLaunchKernelGGL(transpose_y_kernel,dim3(32, 8, 8),  dim3(256), 0, stream, y, yT);
    hipLaunchKernelGGL(gemm_kernel,       dim3(16, 4, 8),  dim3(256), 0, stream,
                       Wb, yT, bias, out);
}

// Round 8
// 211.040 us; speedup vs baseline: 1.7228x; 1.0541x over previous
//
#include <hip/hip_runtime.h>
#include <hip/hip_bf16.h>

#define B_  8
#define H_  512
#define L_  2048
#define D2_ 32
#define NC_ 64
#define LC_ 32    // L_/NC_
#define LCF 32    // fk kernel l-chunk

typedef __attribute__((ext_vector_type(8))) short short8;   // 8 bf16 (4 VGPRs)
typedef __attribute__((ext_vector_type(4))) float float4v;  // 4 fp32 acc
typedef __attribute__((ext_vector_type(2))) float f32x2;    // packed fp32 (v_pk_*)

__device__ __forceinline__ f32x2 pk_fma(f32x2 a, f32x2 b, f32x2 c) {
    return __builtin_elementwise_fma(a, b, c);
}

__device__ __forceinline__ float gelu_exact(float x) {
    return 0.5f * x * (1.0f + erff(x * 0.70710678118654752f));
}

__device__ __forceinline__ unsigned pack_bf16x2(float x, float y) {
    __hip_bfloat162 p = __float22bfloat162_rn(make_float2(x, y));
    return *(unsigned*)&p;
}
__device__ __forceinline__ float2 unpack_bf16x2(unsigned v) {
    __hip_bfloat162 p = *(__hip_bfloat162*)&v;
    return __bfloat1622float2(p);
}

__device__ __forceinline__ void load_lds16(const void* g, void* l) {
    __builtin_amdgcn_global_load_lds((const __attribute__((address_space(1))) unsigned int*)g,
                                     (__attribute__((address_space(3))) unsigned int*)l, 16, 0, 0);
}

// ---------------- cast W -> bf16, fused param prep ----------------
__global__ void cast_prep_kernel(const float* __restrict__ W, __hip_bfloat16* __restrict__ Wb,
                                 const float* __restrict__ a, const float* __restrict__ th,
                                 const float* __restrict__ bb, const float* __restrict__ cc,
                                 const float* __restrict__ x0,
                                 float* __restrict__ aT, float* __restrict__ thT,
                                 float* __restrict__ qT, float* __restrict__ gxT,
                                 float* __restrict__ WRh, float* __restrict__ WIh,
                                 float* __restrict__ QSh) {
    int tid = blockIdx.x * 256 + threadIdx.x;   // 262144
    Wb[tid] = __float2bfloat16(W[tid]);
    if (tid < H_ * D2_) {                        // tid = d*H + h (d-major)
        int h = tid & (H_ - 1);
        int d = tid >> 9;
        const float T = 1.0f / (float)(L_ - 1);
        float av = -fabsf(a[h * D2_ + d]);
        float tv = th[h * D2_ + d];
        float q  = bb[h * D2_ + d] * cc[h * D2_ + d];
        float e  = __expf(av * T);
        aT[tid]  = av;
        thT[tid] = tv;
        qT[tid]  = q;
        gxT[tid] = 2.0f * cc[h * D2_ + d] * x0[h * D2_ + d];
        WRh[h * D2_ + d] = e * __cosf(tv * T);   // h-major for scan kernels
        WIh[h * D2_ + d] = e * __sinf(tv * T);
        QSh[h * D2_ + d] = 2.0f * T * q;
    }
}

// ---------------- fk: FKf[h*L + l] = bf16x2{ f[h,l], k0[h,l] } ----------------
__global__ __launch_bounds__(256) void fk_kernel(
        const float* __restrict__ aT, const float* __restrict__ thT,
        const float* __restrict__ qT, const float* __restrict__ gxT,
        unsigned* __restrict__ FKf) {
    int t = threadIdx.x;
    int q4 = t & 3, hl = t >> 2;
    int h  = blockIdx.y * 64 + hl;
    int l0 = blockIdx.x * LCF;
    const float T = 1.0f / (float)(L_ - 1);
    float z0 = T * (float)l0;
    float pr[8], pi[8], wr[8], wi[8], qd[8], gx[8];
    #pragma unroll
    for (int j = 0; j < 8; ++j) {
        int idx = (q4 * 8 + j) * H_ + h;
        float aa = aT[idx], tv = thT[idx];
        float e0 = __expf(aa * z0);
        pr[j] = e0 * __cosf(tv * z0);
        pi[j] = e0 * __sinf(tv * z0);
        float e1 = __expf(aa * T);
        wr[j] = e1 * __cosf(tv * T);
        wi[j] = e1 * __sinf(tv * T);
        qd[j] = qT[idx];
        gx[j] = gxT[idx];
    }
    for (int i = 0; i < LCF; ++i) {
        float fa = 0.f, ka = 0.f;
        #pragma unroll
        for (int j = 0; j < 8; ++j) {
            fa = fmaf(qd[j], pr[j], fa);
            ka = fmaf(gx[j], pr[j], ka);
            float nr = fmaf(pr[j], wr[j], -(pi[j] * wi[j]));
            float ni = fmaf(pr[j], wi[j],  (pi[j] * wr[j]));
            pr[j] = nr; pi[j] = ni;
        }
        fa += __shfl_xor(fa, 1); fa += __shfl_xor(fa, 2);
        ka += __shfl_xor(ka, 1); ka += __shfl_xor(ka, 2);
        if (q4 == 0)
            FKf[(size_t)h * L_ + l0 + i] = pack_bf16x2(2.0f * T * fa, ka);
    }
}

// ---------------- Pass A: 1 wave per (b,h); stage u->LDS; lane=chunk; pk math ----------------
__global__ __launch_bounds__(64) void scan_a_kernel(
        const float* __restrict__ u, const float* __restrict__ WRh,
        const float* __restrict__ WIh, unsigned* __restrict__ E) {
    __shared__ float u_lds[64 * 33];
    int h = blockIdx.x, b = blockIdx.y;
    int t = threadIdx.x;                // lane = chunk c
    const float* ug = u + (size_t)(b * H_ + h) * L_;
    #pragma unroll
    for (int i = 0; i < 8; ++i) {      // coalesced 1KB/wave/iter -> padded LDS
        float4 v = *(const float4*)(ug + i * 256 + t * 4);
        *(float4*)&u_lds[(i * 8 + (t >> 3)) * 33 + (t & 7) * 4] = v;
    }
    f32x2 wr2[16], wi2[16], sr2[16], si2[16];
    #pragma unroll
    for (int j = 0; j < 16; ++j) {
        float2 wrv = *(const float2*)(WRh + h * D2_ + 2 * j);   // wave-uniform
        float2 wiv = *(const float2*)(WIh + h * D2_ + 2 * j);
        wr2[j] = (f32x2){wrv.x, wrv.y};
        wi2[j] = (f32x2){wiv.x, wiv.y};
        sr2[j] = (f32x2){0.f, 0.f};
        si2[j] = (f32x2){0.f, 0.f};
    }
    int c = t;
    #pragma unroll
    for (int k = 0; k < 8; ++k) {
        float4 u4 = *(const float4*)&u_lds[c * 33 + k * 4];
        float us[4] = {u4.x, u4.y, u4.z, u4.w};
        #pragma unroll
        for (int e = 0; e < 4; ++e) {
            f32x2 ul2 = (f32x2){us[e], us[e]};
            #pragma unroll
            for (int j = 0; j < 16; ++j) {
                f32x2 nr = pk_fma(sr2[j], wr2[j], pk_fma(-si2[j], wi2[j], ul2));
                f32x2 ni = pk_fma(sr2[j], wi2[j], si2[j] * wr2[j]);
                sr2[j] = nr; si2[j] = ni;
            }
        }
    }
    uint4* ep = (uint4*)(E + ((size_t)(b * H_ + h) * NC_ + c) * D2_);
    #pragma unroll
    for (int k = 0; k < 8; ++k) {      // d = 4k..4k+3 -> pairs j=2k,2k+1
        uint4 ev;
        ev.x = pack_bf16x2(sr2[2 * k].x,     si2[2 * k].x);
        ev.y = pack_bf16x2(sr2[2 * k].y,     si2[2 * k].y);
        ev.z = pack_bf16x2(sr2[2 * k + 1].x, si2[2 * k + 1].x);
        ev.w = pack_bf16x2(sr2[2 * k + 1].y, si2[2 * k + 1].y);
        ep[k] = ev;
    }
}

// ---------------- combine: in-place E[c] -> carry ENTERING chunk c ----------------
__global__ __launch_bounds__(256) void combine_kernel(
        const float* __restrict__ a, const float* __restrict__ th,
        unsigned* __restrict__ E) {
    int tid = blockIdx.x * 256 + threadIdx.x;   // B_*H_*D2_ = 131072
    int d  = tid & (D2_ - 1);
    int bh = tid >> 5;
    int h  = bh & (H_ - 1);
    const float T = 1.0f / (float)(L_ - 1);
    float aa  = -fabsf(a[h * D2_ + d]);
    float eC  = __expf(aa * T * (float)LC_);
    float tC  = th[h * D2_ + d] * T * (float)LC_;
    float Wr  = eC * __cosf(tC);
    float Wi  = eC * __sinf(tC);
    float sr = 0.f, si = 0.f;
    for (int c0 = 0; c0 < NC_; c0 += 8) {
        float2 e[8];
        #pragma unroll
        for (int k = 0; k < 8; ++k)
            e[k] = unpack_bf16x2(E[((size_t)bh * NC_ + c0 + k) * D2_ + d]);
        #pragma unroll
        for (int k = 0; k < 8; ++k) {
            E[((size_t)bh * NC_ + c0 + k) * D2_ + d] = pack_bf16x2(sr, si);
            float nr = fmaf(sr, Wr, fmaf(-si, Wi, e[k].x));
            float ni = fmaf(sr, Wi, fmaf(si, Wr, e[k].y));
            sr = nr; si = ni;
        }
    }
}

// ---------------- Pass B: 1 wave per (b,h); u+fk staged in LDS; pk math ----------------
__global__ __launch_bounds__(64) void scan_b_kernel(
        const float* __restrict__ u, const float* __restrict__ WRh,
        const float* __restrict__ WIh, const float* __restrict__ QSh,
        const float* __restrict__ Dp, const unsigned* __restrict__ E,
        const unsigned* __restrict__ FKf, __hip_bfloat16* __restrict__ y) {
    __shared__ float    u_lds[64 * 33];
    __shared__ unsigned f_lds[64 * 33];
    int h = blockIdx.x, b = blockIdx.y;
    int t = threadIdx.x;                // lane = chunk c
    const float*    ug = u + (size_t)(b * H_ + h) * L_;
    const unsigned* fg = FKf + (size_t)h * L_;
    #pragma unroll
    for (int i = 0; i < 8; ++i) {
        float4 v = *(const float4*)(ug + i * 256 + t * 4);
        uint4  f = *(const uint4*)(fg + i * 256 + t * 4);
        int base = (i * 8 + (t >> 3)) * 33 + (t & 7) * 4;
        *(float4*)&u_lds[base] = v;
        *(uint4*)&f_lds[base]  = f;
    }

    f32x2 wr2[16], wi2[16], qs2[16];
    float f0 = 0.f;
    #pragma unroll
    for (int j = 0; j < 16; ++j) {
        float2 wrv = *(const float2*)(WRh + h * D2_ + 2 * j);   // wave-uniform
        float2 wiv = *(const float2*)(WIh + h * D2_ + 2 * j);
        float2 qv  = *(const float2*)(QSh + h * D2_ + 2 * j);
        wr2[j] = (f32x2){wrv.x, wrv.y};
        wi2[j] = (f32x2){wiv.x, wiv.y};
        qs2[j] = (f32x2){qv.x, qv.y};
        f0 += qv.x + qv.y;
    }
    float Dh = Dp[h];
    float c0 = Dh - 0.5f * f0;          // coeff of u[l]

    int c = t;
    f32x2 sr2[16], si2[16];
    const uint4* ep = (const uint4*)(E + ((size_t)(b * H_ + h) * NC_ + c) * D2_);
    #pragma unroll
    for (int k = 0; k < 8; ++k) {       // coalesced 128B/lane
        uint4 ev = ep[k];
        float2 s0 = unpack_bf16x2(ev.x), s1 = unpack_bf16x2(ev.y);
        float2 s2 = unpack_bf16x2(ev.z), s3 = unpack_bf16x2(ev.w);
        sr2[2 * k]     = (f32x2){s0.x, s1.x};
        si2[2 * k]     = (f32x2){s0.y, s1.y};
        sr2[2 * k + 1] = (f32x2){s2.x, s3.x};
        si2[2 * k + 1] = (f32x2){s2.y, s3.y};
    }
    float u0 = u_lds[0];                // u[bh*L + 0], LDS broadcast
    float c1 = -0.5f * u0;              // coeff of f[l]

    unsigned yw[16];
    #pragma unroll
    for (int k = 0; k < 8; ++k) {
        float4 u4 = *(const float4*)&u_lds[c * 33 + k * 4];
        uint4  f4 = *(const uint4*)&f_lds[c * 33 + k * 4];
        float us[4] = {u4.x, u4.y, u4.z, u4.w};
        unsigned fs[4] = {f4.x, f4.y, f4.z, f4.w};
        float g[4];
        #pragma unroll
        for (int e = 0; e < 4; ++e) {
            float2 fk = unpack_bf16x2(fs[e]);
            f32x2 ul2 = (f32x2){us[e], us[e]};
            f32x2 da = (f32x2){0.f, 0.f}, db = (f32x2){0.f, 0.f};
            #pragma unroll
            for (int j = 0; j < 16; ++j) {
                f32x2 nr = pk_fma(sr2[j], wr2[j], pk_fma(-si2[j], wi2[j], ul2));
                f32x2 ni = pk_fma(sr2[j], wi2[j], si2[j] * wr2[j]);
                sr2[j] = nr; si2[j] = ni;
                if (j & 1) db = pk_fma(qs2[j], nr, db);
                else       da = pk_fma(qs2[j], nr, da);
            }
            float dot = (da.x + da.y) + (db.x + db.y);
            float yv = fmaf(c0, us[e], fmaf(c1, fk.x, dot + fk.y));
            g[e] = gelu_exact(yv);
        }
        yw[2 * k]     = pack_bf16x2(g[0], g[1]);
        yw[2 * k + 1] = pack_bf16x2(g[2], g[3]);
    }
    uint4* yp = (uint4*)(y + (size_t)(b * H_ + h) * L_ + c * LC_);
    yp[0] = make_uint4(yw[0],  yw[1],  yw[2],  yw[3]);
    yp[1] = make_uint4(yw[4],  yw[5],  yw[6],  yw[7]);
    yp[2] = make_uint4(yw[8],  yw[9],  yw[10], yw[11]);
    yp[3] = make_uint4(yw[12], yw[13], yw[14], yw[15]);
}

// ---------------- transpose y[b][f][l] -> yT[b][l][f] (bf16) ----------------
__global__ __launch_bounds__(256) void transpose_y_kernel(
        const __hip_bfloat16* __restrict__ y, __hip_bfloat16* __restrict__ yT) {
    __shared__ short tile[64][72];
    int l0 = blockIdx.x * 64, f0 = blockIdx.y * 64, b = blockIdx.z;
    int t = threadIdx.x;
    int row = t >> 3, col8 = (t & 7) * 8;
    const short* yg = (const short*)y + (size_t)b * H_ * L_;
    #pragma unroll
    for (int r2 = 0; r2 < 64; r2 += 32)
        *(uint4*)&tile[row + r2][col8] =
            *(const uint4*)&yg[(size_t)(f0 + row + r2) * L_ + l0 + col8];
    __syncthreads();
    short* og = (short*)yT + (size_t)b * L_ * H_;
    #pragma unroll
    for (int r2 = 0; r2 < 64; r2 += 32) {
        int lrow = row + r2;
        short v[8];
        #pragma unroll
        for (int j = 0; j < 8; ++j) v[j] = tile[col8 + j][lrow];
        *(uint4*)&og[(size_t)(l0 + lrow) * H_ + f0 + col8] = *(uint4*)v;
    }
}

// ---------------- gemm: out[b,h,l] = sum_f W[h,f] * yT[b,l,f] + bias[h] ----------------
__global__ __launch_bounds__(256) void gemm_kernel(
        const __hip_bfloat16* __restrict__ Wb, const __hip_bfloat16* __restrict__ yT,
        const float* __restrict__ bias, float* __restrict__ out) {
    __shared__ __align__(16) short As[128 * 32];
    __shared__ __align__(16) short Bs[128 * 32];
    int l0 = blockIdx.x * 128;
    int h0 = blockIdx.y * 128;
    int b  = blockIdx.z;
    int t    = threadIdx.x;
    int lane = t & 63, wave = t >> 6;
    int m_off = (wave >> 1) * 64, n_off = (wave & 1) * 64;
    int quad = lane >> 4, ln = lane & 15;

    float4v acc[4][4];
    #pragma unroll
    for (int mt = 0; mt < 4; ++mt)
        #pragma unroll
        for (int nt = 0; nt < 4; ++nt)
            acc[mt][nt] = (float4v){0.f, 0.f, 0.f, 0.f};

    const short* Wg = (const short*)Wb;
    const short* Yg = (const short*)(yT + (size_t)b * L_ * H_);

    int r  = t >> 2;
    int qd = t & 3;

    for (int kt = 0; kt < 16; ++kt) {
        int k0 = kt * 32;
        load_lds16(Wg + (h0 + r)      * 512 + k0 + qd * 8, &As[t * 8]);
        load_lds16(Wg + (h0 + r + 64) * 512 + k0 + qd * 8, &As[(t + 256) * 8]);
        load_lds16(Yg + (size_t)(l0 + r)      * 512 + k0 + qd * 8, &Bs[t * 8]);
        load_lds16(Yg + (size_t)(l0 + r + 64) * 512 + k0 + qd * 8, &Bs[(t + 256) * 8]);
        __syncthreads();

        short8 af[4], bf[4];
        #pragma unroll
        for (int mt = 0; mt < 4; ++mt)
            af[mt] = *(const short8*)&As[(m_off + mt * 16 + ln) * 32 + quad * 8];
        #pragma unroll
        for (int nt = 0; nt < 4; ++nt)
            bf[nt] = *(const short8*)&Bs[(n_off + nt * 16 + ln) * 32 + quad * 8];
        #pragma unroll
        for (int mt = 0; mt < 4; ++mt)
            #pragma unroll
            for (int nt = 0; nt < 4; ++nt)
                acc[mt][nt] = __builtin_amdgcn_mfma_f32_16x16x32_bf16(
                    af[mt], bf[nt], acc[mt][nt], 0, 0, 0);
        __syncthreads();
    }

    #pragma unroll
    for (int mt = 0; mt < 4; ++mt) {
        #pragma unroll
        for (int nt = 0; nt < 4; ++nt) {
            int hh = h0 + m_off + mt * 16 + quad * 4;
            int ll = l0 + n_off + nt * 16 + ln;
            #pragma unroll
            for (int r2 = 0; r2 < 4; ++r2)
                out[((size_t)(b * H_ + hh + r2)) * L_ + ll] = acc[mt][nt][r2] + bias[hh + r2];
        }
    }
}

extern "C" void kernel_launch(void* const* d_in, const int* in_sizes, int n_in,
                              void* d_out, int out_size, void* d_ws, size_t ws_size,
                              hipStream_t stream) {
    const float* u    = (const float*)d_in[0];
    const float* a    = (const float*)d_in[1];
    const float* th   = (const float*)d_in[2];
    const float* bb   = (const float*)d_in[3];
    const float* cc   = (const float*)d_in[4];
    const float* x0   = (const float*)d_in[5];
    const float* Dp   = (const float*)d_in[6];
    const float* W    = (const float*)d_in[7];
    const float* bias = (const float*)d_in[8];
    float* out = (float*)d_out;
    char* ws = (char*)d_ws;

    // layout (~53 MB): FKf 4M @0 | E 32M @4M | y 16M @36M | Wb 0.5M @52M | params @52.5M
    // yT 16M @4M ALIASES E (E last read by scan_b; transpose_y writes yT after —
    // sequential stream; pattern proven in R6/R7). ws_size >= 57 MiB proven in R3.
    unsigned*       FKf = (unsigned*)ws;
    unsigned*       E   = (unsigned*)(ws + (4ull  << 20));
    __hip_bfloat16* yT  = (__hip_bfloat16*)(ws + (4ull  << 20));
    __hip_bfloat16* y   = (__hip_bfloat16*)(ws + (36ull << 20));
    __hip_bfloat16* Wb  = (__hip_bfloat16*)(ws + (52ull << 20));
    float* pbase = (float*)(ws + (52ull << 20) + (512ull << 10));
    float *aT  = pbase,            *thT = pbase + 16384,   *qT  = pbase + 2*16384,
          *gxT = pbase + 3*16384,  *WRh = pbase + 4*16384, *WIh = pbase + 5*16384,
          *QSh = pbase + 6*16384;

    hipLaunchKernelGGL(cast_prep_kernel,  dim3(1024),      dim3(256), 0, stream,
                       W, Wb, a, th, bb, cc, x0, aT, thT, qT, gxT, WRh, WIh, QSh);
    hipLaunchKernelGGL(fk_kernel,         dim3(L_/LCF, 8), dim3(256), 0, stream,
                       aT, thT, qT, gxT, FKf);
    hipLaunchKernelGGL(scan_a_kernel,     dim3(H_, B_),    dim3(64),  0, stream,
                       u, WRh, WIh, E);
    hipLaunchKernelGGL(combine_kernel,    dim3(512),       dim3(256), 0, stream, a, th, E);
    hipLaunchKernelGGL(scan_b_kernel,     dim3(H_, B_),    dim3(64),  0, stream,
                       u, WRh, WIh, QSh, Dp, E, FKf, y);
    hipLaunchKernelGGL(transpose_y_kernel,dim3(32, 8, 8),  dim3(256), 0, stream, y, yT);
    hipLaunchKernelGGL(gemm_kernel,       dim3(16, 4, 8),  dim3(256), 0, stream,
                       Wb, yT, bias, out);
}